// Round 2
// 9126.910 us; speedup vs baseline: 1.2021x; 1.2021x over previous
//
#include <hip/hip_runtime.h>
#include <hip/hip_cooperative_groups.h>

namespace cg = cooperative_groups;

typedef short short8 __attribute__((ext_vector_type(8)));
typedef float f32x4 __attribute__((ext_vector_type(4)));
typedef unsigned short ushortT;

// ---------- helpers ----------
__device__ __forceinline__ ushortT f2bf(float f) {
    unsigned int u = __builtin_bit_cast(unsigned int, f);
    unsigned int r = u + 0x7fffu + ((u >> 16) & 1u);
    return (ushortT)(r >> 16);
}
__device__ __forceinline__ float bf2f(ushortT u) {
    unsigned int x = ((unsigned int)u) << 16;
    return __builtin_bit_cast(float, x);
}
__device__ __forceinline__ float sigm(float x) { return 1.f / (1.f + __expf(-x)); }
__device__ __forceinline__ float tanh_fast(float x) {
    x = fminf(fmaxf(x, -15.f), 15.f);
    float e = __expf(2.f * x);
    return (e - 1.f) / (e + 1.f);
}
__device__ __forceinline__ float dot4(float4 a, float4 b) {
    return a.x*b.x + a.y*b.y + a.z*b.z + a.w*b.w;
}

// ---------- tiny prep kernels ----------
__global__ void prep_bias(const float* __restrict__ bihf, const float* __restrict__ bhhf,
                          const float* __restrict__ bihb, const float* __restrict__ bhhb,
                          const float* __restrict__ bihd, const float* __restrict__ bhhd,
                          float* __restrict__ bf_, float* __restrict__ bb_, float* __restrict__ bd_) {
    int id = blockIdx.x * 256 + threadIdx.x;     // 12288
    int mt = id >> 12, n = id & 4095;
    if (mt == 0) bf_[n] = bihf[n] + bhhf[n];
    else if (mt == 1) bb_[n] = bihb[n] + bhhb[n];
    else bd_[n] = bihd[n] + bhhd[n];
}

// embedding gather + bf16 split (x and y)
__global__ void embed_split(const int* __restrict__ inputs, const int* __restrict__ targets,
                            const float* __restrict__ es, const float* __restrict__ et,
                            ushortT* __restrict__ x1, ushortT* __restrict__ x2,
                            ushortT* __restrict__ y1, ushortT* __restrict__ y2) {
    int row = blockIdx.x;            // 0..4095
    int tid = threadIdx.x;           // 128
    bool isx = row < 2048;
    int r = isx ? row : row - 2048;
    int idx = isx ? inputs[r] : targets[r];
    const float* src = (isx ? es : et) + (size_t)idx * 512;
    float4 v = *(const float4*)&src[tid * 4];
    ushort4 hi, lo;
    hi.x = f2bf(v.x); lo.x = f2bf(v.x - bf2f(hi.x));
    hi.y = f2bf(v.y); lo.y = f2bf(v.y - bf2f(hi.y));
    hi.z = f2bf(v.z); lo.z = f2bf(v.z - bf2f(hi.z));
    hi.w = f2bf(v.w); lo.w = f2bf(v.w - bf2f(hi.w));
    ushortT* o1 = isx ? x1 : y1;
    ushortT* o2 = isx ? x2 : y2;
    *(ushort4*)&o1[(size_t)r * 512 + tid * 4] = hi;
    *(ushort4*)&o2[(size_t)r * 512 + tid * 4] = lo;
}

__global__ void split_pair(const float* __restrict__ in, ushortT* __restrict__ o1,
                           ushortT* __restrict__ o2, int n4) {
    for (int i = blockIdx.x * blockDim.x + threadIdx.x; i < n4; i += gridDim.x * blockDim.x) {
        float4 v = ((const float4*)in)[i];
        ushort4 hi, lo;
        hi.x = f2bf(v.x); lo.x = f2bf(v.x - bf2f(hi.x));
        hi.y = f2bf(v.y); lo.y = f2bf(v.y - bf2f(hi.y));
        hi.z = f2bf(v.z); lo.z = f2bf(v.z - bf2f(hi.z));
        hi.w = f2bf(v.w); lo.w = f2bf(v.w - bf2f(hi.w));
        ((ushort4*)o1)[i] = hi;
        ((ushort4*)o2)[i] = lo;
    }
}

__global__ void conv_single(const float* __restrict__ in, ushortT* __restrict__ o1, int n4) {
    for (int i = blockIdx.x * blockDim.x + threadIdx.x; i < n4; i += gridDim.x * blockDim.x) {
        float4 v = ((const float4*)in)[i];
        ushort4 hi;
        hi.x = f2bf(v.x); hi.y = f2bf(v.y); hi.z = f2bf(v.z); hi.w = f2bf(v.w);
        ((ushort4*)o1)[i] = hi;
    }
}

// Wc[:, :1024] split (row stride 3072)
__global__ void wc_split(const float* __restrict__ Wc, ushortT* __restrict__ o1, ushortT* __restrict__ o2) {
    int id = blockIdx.x * 256 + threadIdx.x;   // 1024*256
    int n = id >> 8, k4 = id & 255;
    float4 v = *(const float4*)&Wc[(size_t)n * 3072 + k4 * 4];
    ushort4 hi, lo;
    hi.x = f2bf(v.x); lo.x = f2bf(v.x - bf2f(hi.x));
    hi.y = f2bf(v.y); lo.y = f2bf(v.y - bf2f(hi.y));
    hi.z = f2bf(v.z); lo.z = f2bf(v.z - bf2f(hi.z));
    hi.w = f2bf(v.w); lo.w = f2bf(v.w - bf2f(hi.w));
    *(ushort4*)&o1[(size_t)n * 1024 + k4 * 4] = hi;
    *(ushort4*)&o2[(size_t)n * 1024 + k4 * 4] = lo;
}

// Whh (4096x1024) -> wt3[dir][k>>2][col][gate][k&3]  (fp32)
__global__ __launch_bounds__(256, 1) void transpose_whh(
    const float* __restrict__ Wf, const float* __restrict__ Wb, const float* __restrict__ Wd,
    float* __restrict__ wt3) {
    __shared__ float lds[64 * 132];
    int bx = blockIdx.x;             // 3*32*16 = 1536
    int d = bx >> 9;
    int rem = bx & 511;
    int kt = rem >> 4;               // 0..31 : 32-k tile
    int ct = rem & 15;               // 0..15 : 64-col tile
    const float* W = (d == 0) ? Wf : (d == 1) ? Wb : Wd;
    float* out = wt3 + (size_t)d * 4194304;
    int tid = threadIdx.x;
#pragma unroll
    for (int i = 0; i < 8; ++i) {
        int id = i * 256 + tid;
        int k8 = id & 7;             // float4 over k
        int rc = id >> 3;
        int g = rc >> 6, c = rc & 63;
        float4 v = *(const float4*)&W[(size_t)(g * 1024 + ct * 64 + c) * 1024 + kt * 32 + k8 * 4];
        lds[c * 132 + (k8 * 4 + 0) * 4 + g] = v.x;
        lds[c * 132 + (k8 * 4 + 1) * 4 + g] = v.y;
        lds[c * 132 + (k8 * 4 + 2) * 4 + g] = v.z;
        lds[c * 132 + (k8 * 4 + 3) * 4 + g] = v.w;
    }
    __syncthreads();
#pragma unroll
    for (int i = 0; i < 8; ++i) {
        int id = i * 256 + tid;
        int k4l = id >> 8;           // 0..7
        int rem2 = id & 255;
        int c = rem2 >> 2, g = rem2 & 3;
        float4 v;
        v.x = lds[c * 132 + (k4l * 4 + 0) * 4 + g];
        v.y = lds[c * 132 + (k4l * 4 + 1) * 4 + g];
        v.z = lds[c * 132 + (k4l * 4 + 2) * 4 + g];
        v.w = lds[c * 132 + (k4l * 4 + 3) * 4 + g];
        *(float4*)&out[(size_t)((kt * 8 + k4l) * 1024 + ct * 64 + c) * 16 + g * 4] = v;
    }
}

// ---------- MFMA GEMM: C[m][n] = sum_k A[m][k]*B[n][k] (+ bias / epilogue) ----------
// MODE 0: split3 (A1B1+A1B2+A2B1), C = acc + bias[n]
// MODE 1: split3, C = tanh(acc + bias[(m>>6)*1024 + n]); dual store f32 + bf16
// MODE 2: single (A1B1), C = acc + bias[n]
template <int MODE>
__global__ __launch_bounds__(256, 1) void gemm_bt(
    const ushortT* __restrict__ A1, const ushortT* __restrict__ A2,
    const ushortT* __restrict__ B1, const ushortT* __restrict__ B2,
    float* __restrict__ C, ushortT* __restrict__ Cb,
    const float* __restrict__ bias, int M, int N, int K) {
    constexpr int NBUF = (MODE == 2) ? 2 : 4;
    __shared__ __align__(16) ushortT smem[NBUF * 128 * 40];
    ushortT* sA1 = smem;
    ushortT* sB1 = smem + 128 * 40;
    ushortT* sA2 = smem + 2 * 128 * 40;   // unused when MODE==2
    ushortT* sB2 = smem + 3 * 128 * 40;

    const int tid = threadIdx.x;
    const int bm = blockIdx.y, bn = blockIdx.x;
    const int w = tid >> 6, lane = tid & 63;
    const int wm = (w & 1) * 64, wn = (w >> 1) * 64;
    const int lr = lane & 15, lq = lane >> 4;

    f32x4 acc[4][4] = {};
    const int nkt = K >> 5;
    for (int kt = 0; kt < nkt; ++kt) {
        __syncthreads();
#pragma unroll
        for (int i = 0; i < 2; ++i) {
            int id = tid + i * 256;
            int row = id >> 2, kc = id & 3;
            int so = row * 40 + kc * 8;
            size_t goA = (size_t)(bm * 128 + row) * K + kt * 32 + kc * 8;
            size_t goB = (size_t)(bn * 128 + row) * K + kt * 32 + kc * 8;
            *(uint4*)&sA1[so] = *(const uint4*)&A1[goA];
            *(uint4*)&sB1[so] = *(const uint4*)&B1[goB];
            if (MODE != 2) {
                *(uint4*)&sA2[so] = *(const uint4*)&A2[goA];
                *(uint4*)&sB2[so] = *(const uint4*)&B2[goB];
            }
        }
        __syncthreads();
        short8 a1[4], b1[4];
#pragma unroll
        for (int i = 0; i < 4; ++i) {
            a1[i] = *(const short8*)&sA1[(wm + i * 16 + lr) * 40 + lq * 8];
            b1[i] = *(const short8*)&sB1[(wn + i * 16 + lr) * 40 + lq * 8];
        }
        if (MODE == 2) {
#pragma unroll
            for (int mt = 0; mt < 4; ++mt)
#pragma unroll
                for (int nt = 0; nt < 4; ++nt)
                    acc[mt][nt] = __builtin_amdgcn_mfma_f32_16x16x32_bf16(a1[mt], b1[nt], acc[mt][nt], 0, 0, 0);
        } else {
            short8 a2[4], b2[4];
#pragma unroll
            for (int i = 0; i < 4; ++i) {
                a2[i] = *(const short8*)&sA2[(wm + i * 16 + lr) * 40 + lq * 8];
                b2[i] = *(const short8*)&sB2[(wn + i * 16 + lr) * 40 + lq * 8];
            }
#pragma unroll
            for (int mt = 0; mt < 4; ++mt)
#pragma unroll
                for (int nt = 0; nt < 4; ++nt) {
                    f32x4 a = acc[mt][nt];
                    a = __builtin_amdgcn_mfma_f32_16x16x32_bf16(a2[mt], b1[nt], a, 0, 0, 0);
                    a = __builtin_amdgcn_mfma_f32_16x16x32_bf16(a1[mt], b2[nt], a, 0, 0, 0);
                    a = __builtin_amdgcn_mfma_f32_16x16x32_bf16(a1[mt], b1[nt], a, 0, 0, 0);
                    acc[mt][nt] = a;
                }
        }
    }
    // epilogue; C row=m=(lane>>4)*4+reg, col=n=lane&15 (verified gfx950 mapping)
#pragma unroll
    for (int nt = 0; nt < 4; ++nt) {
        int gn = bn * 128 + wn + nt * 16 + lr;
        float bv = (MODE == 1) ? 0.f : bias[gn];
#pragma unroll
        for (int mt = 0; mt < 4; ++mt) {
            int gmb = bm * 128 + wm + mt * 16 + lq * 4;
#pragma unroll
            for (int r = 0; r < 4; ++r) {
                int gm = gmb + r;
                float v = acc[mt][nt][r];
                if (MODE == 1) {
                    v += bias[(gm >> 6) * 1024 + gn];
                    v = tanhf(v);
                    C[(size_t)gm * N + gn] = v;
                    Cb[(size_t)gm * N + gn] = f2bf(v);
                } else {
                    C[(size_t)gm * N + gn] = v + bv;
                }
            }
        }
    }
}

// ---------- encoder: fused fwd+bwd LSTM, 64 steps, 1 grid.sync/step ----------
// 256 wgs x 1024 threads (16 waves/CU = 4 waves/SIMD).
// K=1024 dot split 4 ways across wave-quads (kc), LDS cross-wave reduce per step.
// h read direct from global (L2-resident); no LDS staging.
__global__ __launch_bounds__(1024, 4) void encoder_kernel(
    const float* __restrict__ wt3,       // [2][256][1024][16]
    const float* __restrict__ Gf, const float* __restrict__ Gb,
    float* __restrict__ ench,            // [2 buf][2 dir][32768]
    float* __restrict__ cfin,            // [32768] (dir1 final c)
    float* __restrict__ applied,         // [32][2048]
    float* __restrict__ dech,            // [2][32768]
    float* __restrict__ cdec) {          // [32768]
    cg::grid_group grid = cg::this_grid();
    const int wg = blockIdx.x;           // 256
    const int dir = wg & 1;
    const int cb8 = wg >> 1;             // 0..127
    const int tid = threadIdx.x;         // 0..1023
    const int w = tid >> 6;              // 0..15
    const int lane = tid & 63;
    const int c2 = lane >> 5, b = lane & 31;
    const int kc = w >> 2;               // k-chunk 0..3 (256 k each)
    const int wp = w & 3;                // col-pair 0..3
    const int col = cb8 * 8 + wp * 2 + c2;
    const bool upd = (kc == 0);          // wave-uniform
    const float* W = wt3 + (size_t)dir * 4194304;
    const float* G = dir ? Gb : Gf;
    __shared__ __align__(16) float red[4096];   // 16 KB: [w][lane][gate]
    float cc = 0.f, hsum = 0.f, hn = 0.f;
    const int ht4 = (col >> 2) * 128 + b * 4 + (col & 3);
    const float* wpt = W + (size_t)(kc * 64) * 16384 + col * 16;
    for (int t = 0; t < 64; ++t) {
        const int tg = dir ? (63 - t) : t;
        const size_t mo = (size_t)(b * 64 + tg) * 4096 + col;
        float g0 = 0.f, g1 = 0.f, g2 = 0.f, g3 = 0.f;
        if (upd) { g0 = G[mo]; g1 = G[mo + 1024]; g2 = G[mo + 2048]; g3 = G[mo + 3072]; }
        float ai = 0.f, af = 0.f, ag = 0.f, ao = 0.f;
        if (t > 0) {
            const float* hsrc = ench + (size_t)((((t + 1) & 1) * 2) + dir) * 32768 + kc * 8192;
#pragma unroll 4
            for (int k4 = 0; k4 < 64; ++k4) {
                float4 hv = *(const float4*)&hsrc[(k4 * 32 + b) * 4];
                const float* wq = wpt + (size_t)k4 * 16384;
                float4 wi = *(const float4*)(wq);
                float4 wf = *(const float4*)(wq + 4);
                float4 wg_ = *(const float4*)(wq + 8);
                float4 wo = *(const float4*)(wq + 12);
                ai = fmaf(hv.x, wi.x, ai); ai = fmaf(hv.y, wi.y, ai); ai = fmaf(hv.z, wi.z, ai); ai = fmaf(hv.w, wi.w, ai);
                af = fmaf(hv.x, wf.x, af); af = fmaf(hv.y, wf.y, af); af = fmaf(hv.z, wf.z, af); af = fmaf(hv.w, wf.w, af);
                ag = fmaf(hv.x, wg_.x, ag); ag = fmaf(hv.y, wg_.y, ag); ag = fmaf(hv.z, wg_.z, ag); ag = fmaf(hv.w, wg_.w, ag);
                ao = fmaf(hv.x, wo.x, ao); ao = fmaf(hv.y, wo.y, ao); ao = fmaf(hv.z, wo.z, ao); ao = fmaf(hv.w, wo.w, ao);
            }
        }
        // cross-wave (kc) reduction; red written each step, protected by grid.sync of prev step
        *(float4*)&red[tid * 4] = float4{ai, af, ag, ao};
        __syncthreads();
        if (upd) {
            float4 p0 = *(const float4*)&red[(wp * 64 + lane) * 4];
            float4 p1 = *(const float4*)&red[((4 + wp) * 64 + lane) * 4];
            float4 p2 = *(const float4*)&red[((8 + wp) * 64 + lane) * 4];
            float4 p3 = *(const float4*)&red[((12 + wp) * 64 + lane) * 4];
            float gi = g0 + p0.x + p1.x + p2.x + p3.x;
            float gf = g1 + p0.y + p1.y + p2.y + p3.y;
            float gg = g2 + p0.z + p1.z + p2.z + p3.z;
            float go = g3 + p0.w + p1.w + p2.w + p3.w;
            float i_ = sigm(gi), f_ = sigm(gf), g_ = tanh_fast(gg), o_ = sigm(go);
            cc = f_ * cc + i_ * g_;
            hn = o_ * tanh_fast(cc);
            hsum += hn;
            float* hw = ench + (size_t)(((t & 1) * 2) + dir) * 32768;
            hw[ht4] = hn;
            if (t == 63 && dir == 1) cfin[b * 1024 + col] = cc;
        }
        grid.sync();
    }
    if (upd) {
        applied[b * 2048 + dir * 1024 + col] = hsum;
        if (dir == 0) {
            const float* h1d = ench + (size_t)(1 * 2 + 1) * 32768;   // buf1, dir1
            dech[32768 + ht4] = hn + h1d[ht4];                       // seed decoder buf1
            cdec[b * 1024 + col] = cc + cfin[b * 1024 + col];
        }
    }
}

// ---------- decoder LSTM, 64 steps ----------
// 256 wgs x 1024 threads; K split 4 ways across wave-quads (kc), LDS reduce,
// gate-pair (gp) shuffle combine as before.
__global__ __launch_bounds__(1024, 4) void decoder_kernel(
    const float* __restrict__ wt3d,      // [256][1024][16]
    const float* __restrict__ G,
    float* __restrict__ dech,            // [2][32768]
    const float* __restrict__ cdec,
    float* __restrict__ hall,            // [2048][1024] f32
    ushortT* __restrict__ h1, ushortT* __restrict__ h2) {
    cg::grid_group grid = cg::this_grid();
    const int wg = blockIdx.x;           // 256
    const int tid = threadIdx.x;         // 0..1023
    const int w = tid >> 6;              // 0..15
    const int lane = tid & 63;
    const int kc = w >> 2;               // k-chunk 0..3
    const int wsub = w & 3;              // col 0..3 within wg
    const int col = wg * 4 + wsub;       // 0..1023
    const int b = lane & 31, gp = lane >> 5;
    const bool upd = (kc == 0);
    __shared__ __align__(16) float red[2048];   // 8 KB: [w][lane][2]
    float cc = cdec[b * 1024 + col];
    const int ht4 = (col >> 2) * 128 + b * 4 + (col & 3);
    const float* wpt = wt3d + (size_t)(kc * 64) * 16384 + col * 16 + gp * 8;
    for (int t = 0; t < 64; ++t) {
        const size_t mo = (size_t)(b * 64 + t) * 4096 + col;
        float g0 = 0.f, g1 = 0.f, g2 = 0.f, g3 = 0.f;
        if (upd) { g0 = G[mo]; g1 = G[mo + 1024]; g2 = G[mo + 2048]; g3 = G[mo + 3072]; }
        float s0 = 0.f, s1 = 0.f;
        const float* hsrc = dech + (size_t)((t + 1) & 1) * 32768 + kc * 8192;
#pragma unroll 4
        for (int k4 = 0; k4 < 64; ++k4) {
            float4 hv = *(const float4*)&hsrc[(k4 * 32 + b) * 4];
            const float* wq = wpt + (size_t)k4 * 16384;
            float4 wa = *(const float4*)(wq);
            float4 wb_ = *(const float4*)(wq + 4);
            s0 = fmaf(hv.x, wa.x, s0); s0 = fmaf(hv.y, wa.y, s0); s0 = fmaf(hv.z, wa.z, s0); s0 = fmaf(hv.w, wa.w, s0);
            s1 = fmaf(hv.x, wb_.x, s1); s1 = fmaf(hv.y, wb_.y, s1); s1 = fmaf(hv.z, wb_.z, s1); s1 = fmaf(hv.w, wb_.w, s1);
        }
        *(float2*)&red[tid * 2] = float2{s0, s1};
        __syncthreads();
        if (upd) {
            float2 q0 = *(const float2*)&red[(wsub * 64 + lane) * 2];
            float2 q1 = *(const float2*)&red[((4 + wsub) * 64 + lane) * 2];
            float2 q2 = *(const float2*)&red[((8 + wsub) * 64 + lane) * 2];
            float2 q3 = *(const float2*)&red[((12 + wsub) * 64 + lane) * 2];
            s0 = q0.x + q1.x + q2.x + q3.x;
            s1 = q0.y + q1.y + q2.y + q3.y;
            float t0 = __shfl_xor(s0, 32);
            float t1 = __shfl_xor(s1, 32);
            float gi, gf, gg, go;
            if (gp == 0) { gi = s0; gf = s1; gg = t0; go = t1; }
            else         { gi = t0; gf = t1; gg = s0; go = s1; }
            gi += g0; gf += g1; gg += g2; go += g3;
            float i_ = sigm(gi), f_ = sigm(gf), g_ = tanh_fast(gg), o_ = sigm(go);
            cc = f_ * cc + i_ * g_;
            float hn = o_ * tanh_fast(cc);
            if (gp == 0) {
                dech[(size_t)(t & 1) * 32768 + ht4] = hn;
                size_t ho = (size_t)(b * 64 + t) * 1024 + col;
                hall[ho] = hn;
                ushortT hh = f2bf(hn);
                h1[ho] = hh;
                h2[ho] = f2bf(hn - bf2f(hh));
            }
        }
        grid.sync();
    }
}

// ---------- ca[b][n] = bc[n] + sum_k applied[b][k] * Wc[n][1024+k] ----------
__global__ void ca_kernel(const float* __restrict__ applied, const float* __restrict__ Wc,
                          const float* __restrict__ bc, float* __restrict__ ca) {
    int id = blockIdx.x * 256 + threadIdx.x;   // 32768
    int b = id & 31, n = id >> 5;
    const float4* ap = (const float4*)(applied + b * 2048);
    const float4* wp = (const float4*)(Wc + (size_t)n * 3072 + 1024);
    float s = bc[n];
    for (int k = 0; k < 512; ++k) s += dot4(ap[k], wp[k]);
    ca[b * 1024 + n] = s;
}

// ---------- softmax + candidate collection (in-place on logits) ----------
__global__ __launch_bounds__(256, 1) void softmax_kernel(float* __restrict__ out,
                                                         int* __restrict__ cand, int* __restrict__ cnt) {
    int row = blockIdx.x, tid = threadIdx.x;
    float4* p4 = (float4*)(out + (size_t)row * 32000);
    float mx = -1e30f, sm = 0.f;
    for (int i = tid; i < 8000; i += 256) {
        float4 v = p4[i];
        float c;
        c = v.x; if (c > mx) { sm = sm * __expf(mx - c) + 1.f; mx = c; } else sm += __expf(c - mx);
        c = v.y; if (c > mx) { sm = sm * __expf(mx - c) + 1.f; mx = c; } else sm += __expf(c - mx);
        c = v.z; if (c > mx) { sm = sm * __expf(mx - c) + 1.f; mx = c; } else sm += __expf(c - mx);
        c = v.w; if (c > mx) { sm = sm * __expf(mx - c) + 1.f; mx = c; } else sm += __expf(c - mx);
    }
    __shared__ float rm[256], rs[256];
    rm[tid] = mx; rs[tid] = sm;
    __syncthreads();
    for (int off = 128; off > 0; off >>= 1) {
        if (tid < off) {
            float m1 = rm[tid], m2 = rm[tid + off], s1 = rs[tid], s2 = rs[tid + off];
            float mN = fmaxf(m1, m2);
            rm[tid] = mN;
            rs[tid] = s1 * __expf(m1 - mN) + s2 * __expf(m2 - mN);
        }
        __syncthreads();
    }
    float M = rm[0];
    float lse = M + __logf(rs[0]);
    __shared__ int lcnt;
    __shared__ int lcand[128];
    if (tid == 0) lcnt = 0;
    __syncthreads();
    const float thr = M - 6e-3f;
    for (int i = tid; i < 8000; i += 256) {
        float4 v = p4[i];
        float4 o;
        o.x = v.x - lse; o.y = v.y - lse; o.z = v.z - lse; o.w = v.w - lse;
        p4[i] = o;
        if (v.x >= thr) { int pos = atomicAdd(&lcnt, 1); if (pos < 128) lcand[pos] = i * 4 + 0; }
        if (v.y >= thr) { int pos = atomicAdd(&lcnt, 1); if (pos < 128) lcand[pos] = i * 4 + 1; }
        if (v.z >= thr) { int pos = atomicAdd(&lcnt, 1); if (pos < 128) lcand[pos] = i * 4 + 2; }
        if (v.w >= thr) { int pos = atomicAdd(&lcnt, 1); if (pos < 128) lcand[pos] = i * 4 + 3; }
    }
    __syncthreads();
    if (tid < 128 && tid < lcnt) cand[row * 128 + tid] = lcand[tid];
    if (tid == 0) cnt[row] = lcnt;
}

// ---------- fp32 argmax recheck: one wave per row ----------
__global__ __launch_bounds__(256, 1) void recheck_kernel(
    const float* __restrict__ outsf, const float* __restrict__ Wout, const float* __restrict__ bout,
    const int* __restrict__ cand, const int* __restrict__ cnt, float* __restrict__ preds) {
    int w = threadIdx.x >> 6, lane = threadIdx.x & 63;
    int row = blockIdx.x * 4 + w;
    const float4* ar = (const float4*)(outsf + (size_t)row * 1024);
    float4 a0 = ar[lane], a1 = ar[lane + 64], a2 = ar[lane + 128], a3 = ar[lane + 192];
    int n = cnt[row];
    float best = -1e30f;
    int bi = 0;
    if (n <= 128) {
        for (int ci = 0; ci < n; ++ci) {
            int j = cand[row * 128 + ci];
            const float4* wr = (const float4*)(Wout + (size_t)j * 1024);
            float s = dot4(a0, wr[lane]) + dot4(a1, wr[lane + 64]) + dot4(a2, wr[lane + 128]) + dot4(a3, wr[lane + 192]);
            for (int off = 32; off; off >>= 1) s += __shfl_xor(s, off);
            s += bout[j];
            if (s > best || (s == best && j < bi)) { best = s; bi = j; }
        }
    } else {
        for (int j = 0; j < 32000; ++j) {
            const float4* wr = (const float4*)(Wout + (size_t)j * 1024);
            float s = dot4(a0, wr[lane]) + dot4(a1, wr[lane + 64]) + dot4(a2, wr[lane + 128]) + dot4(a3, wr[lane + 192]);
            for (int off = 32; off; off >>= 1) s += __shfl_xor(s, off);
            s += bout[j];
            if (s > best || (s == best && j < bi)) { best = s; bi = j; }
        }
    }
    if (lane == 0) preds[row] = (float)bi;
}

// ---------- host ----------
static inline size_t al256(size_t x) { return (x + 255) & ~(size_t)255; }

extern "C" void kernel_launch(void* const* d_in, const int* in_sizes, int n_in,
                              void* d_out, int out_size, void* d_ws, size_t ws_size,
                              hipStream_t stream) {
    const int* inputs = (const int*)d_in[0];
    const int* targets = (const int*)d_in[1];
    const float* emb_src = (const float*)d_in[2];
    const float* Wih_f = (const float*)d_in[3];
    const float* Whh_f = (const float*)d_in[4];
    const float* bih_f = (const float*)d_in[5];
    const float* bhh_f = (const float*)d_in[6];
    const float* Wih_b = (const float*)d_in[7];
    const float* Whh_b = (const float*)d_in[8];
    const float* bih_b = (const float*)d_in[9];
    const float* bhh_b = (const float*)d_in[10];
    const float* emb_tgt = (const float*)d_in[11];
    const float* Wih_d = (const float*)d_in[12];
    const float* Whh_d = (const float*)d_in[13];
    const float* bih_d = (const float*)d_in[14];
    const float* bhh_d = (const float*)d_in[15];
    // d_in[16] = Wattn: provably unused (softmax over size-1 axis -> weights == 1)
    const float* Wc = (const float*)d_in[17];
    const float* bc = (const float*)d_in[18];
    const float* Wout = (const float*)d_in[19];
    const float* bout = (const float*)d_in[20];

    char* p = (char*)d_ws;
    size_t off = 0;
    auto carve = [&](size_t bytes) { void* r = p + off; off = al256(off + bytes); return r; };

    ushortT* x1 = (ushortT*)carve(2048ull * 512 * 2);
    ushortT* x2 = (ushortT*)carve(2048ull * 512 * 2);
    ushortT* y1 = (ushortT*)carve(2048ull * 512 * 2);
    ushortT* y2 = (ushortT*)carve(2048ull * 512 * 2);
    ushortT* wf1 = (ushortT*)carve(4096ull * 512 * 2);
    ushortT* wf2 = (ushortT*)carve(4096ull * 512 * 2);
    ushortT* wb1 = (ushortT*)carve(4096ull * 512 * 2);
    ushortT* wb2 = (ushortT*)carve(4096ull * 512 * 2);
    ushortT* wd1 = (ushortT*)carve(4096ull * 512 * 2);
    ushortT* wd2 = (ushortT*)carve(4096ull * 512 * 2);
    ushortT* wc1 = (ushortT*)carve(1024ull * 1024 * 2);
    ushortT* wc2 = (ushortT*)carve(1024ull * 1024 * 2);
    ushortT* woutb = (ushortT*)carve(32000ull * 1024 * 2);
    float* biasf = (float*)carve(4096ull * 4);
    float* biasb = (float*)carve(4096ull * 4);
    float* biasd = (float*)carve(4096ull * 4);
    float* wt3 = (float*)carve(3ull * 4194304 * 4);
    float* Gf = (float*)carve(2048ull * 4096 * 4);
    float* Gb = (float*)carve(2048ull * 4096 * 4);
    float* Gd = (float*)carve(2048ull * 4096 * 4);
    float* ench = (float*)carve(4ull * 32768 * 4);
    float* cfin = (float*)carve(32768ull * 4);
    float* applied = (float*)carve(65536ull * 4);
    float* dech = (float*)carve(2ull * 32768 * 4);
    float* cdec = (float*)carve(32768ull * 4);
    float* hall = (float*)carve(2048ull * 1024 * 4);
    ushortT* h1 = (ushortT*)carve(2048ull * 1024 * 2);
    ushortT* h2 = (ushortT*)carve(2048ull * 1024 * 2);
    float* ca = (float*)carve(32768ull * 4);
    float* outsf = (float*)carve(2048ull * 1024 * 4);
    ushortT* outsb = (ushortT*)carve(2048ull * 1024 * 2);
    int* cand = (int*)carve(2048ull * 128 * 4);
    int* cnt = (int*)carve(2048ull * 4);
    (void)ws_size;  // requires ~275 MB of workspace

    float* scores = (float*)d_out;
    float* preds = scores + 65536000ull;

    // prep
    prep_bias<<<48, 256, 0, stream>>>(bih_f, bhh_f, bih_b, bhh_b, bih_d, bhh_d, biasf, biasb, biasd);
    embed_split<<<4096, 128, 0, stream>>>(inputs, targets, emb_src, emb_tgt, x1, x2, y1, y2);
    split_pair<<<1024, 256, 0, stream>>>(Wih_f, wf1, wf2, 524288);
    split_pair<<<1024, 256, 0, stream>>>(Wih_b, wb1, wb2, 524288);
    split_pair<<<1024, 256, 0, stream>>>(Wih_d, wd1, wd2, 524288);
    wc_split<<<1024, 256, 0, stream>>>(Wc, wc1, wc2);
    conv_single<<<2048, 256, 0, stream>>>(Wout, woutb, 8192000);
    transpose_whh<<<1536, 256, 0, stream>>>(Whh_f, Whh_b, Whh_d, wt3);

    // gate precompute (split-bf16, fp32-grade)
    gemm_bt<0><<<dim3(32, 16), 256, 0, stream>>>(x1, x2, wf1, wf2, Gf, nullptr, biasf, 2048, 4096, 512);
    gemm_bt<0><<<dim3(32, 16), 256, 0, stream>>>(x1, x2, wb1, wb2, Gb, nullptr, biasb, 2048, 4096, 512);
    gemm_bt<0><<<dim3(32, 16), 256, 0, stream>>>(y1, y2, wd1, wd2, Gd, nullptr, biasd, 2048, 4096, 512);

    // encoder (cooperative, 1024 threads/wg)
    {
        void* args[] = {&wt3, &Gf, &Gb, &ench, &cfin, &applied, &dech, &cdec};
        hipLaunchCooperativeKernel((void*)encoder_kernel, dim3(256), dim3(1024), args, 0, stream);
    }
    ca_kernel<<<128, 256, 0, stream>>>(applied, Wc, bc, ca);
    // decoder (cooperative, 1024 threads/wg)
    {
        const float* wt3d = wt3 + 2ull * 4194304;
        void* args[] = {&wt3d, &Gd, &dech, &cdec, &hall, &h1, &h2};
        hipLaunchCooperativeKernel((void*)decoder_kernel, dim3(256), dim3(1024), args, 0, stream);
    }

    // outs = tanh(hall @ Wc_h^T + ca)  (split-bf16 + tanh, dual store)
    gemm_bt<1><<<dim3(8, 16), 256, 0, stream>>>(h1, h2, wc1, wc2, outsf, outsb, ca, 2048, 1024, 1024);
    // logits = outs @ Wout^T + bout  (single-pass bf16, straight into d_out)
    gemm_bt<2><<<dim3(250, 16), 256, 0, stream>>>(outsb, nullptr, woutb, nullptr, scores, nullptr, bout, 2048, 32000, 1024);
    // log_softmax in place + candidate collection
    softmax_kernel<<<2048, 256, 0, stream>>>(scores, cand, cnt);
    // fp32 argmax recheck -> preds
    recheck_kernel<<<512, 256, 0, stream>>>(outsf, Wout, bout, cand, cnt, preds);
}

// Round 3
// 6928.397 us; speedup vs baseline: 1.5836x; 1.3173x over previous
//
#include <hip/hip_runtime.h>
#include <hip/hip_cooperative_groups.h>

namespace cg = cooperative_groups;

typedef short short8 __attribute__((ext_vector_type(8)));
typedef float f32x4 __attribute__((ext_vector_type(4)));
typedef unsigned short ushortT;

// ---------- helpers ----------
__device__ __forceinline__ ushortT f2bf(float f) {
    unsigned int u = __builtin_bit_cast(unsigned int, f);
    unsigned int r = u + 0x7fffu + ((u >> 16) & 1u);
    return (ushortT)(r >> 16);
}
__device__ __forceinline__ float bf2f(ushortT u) {
    unsigned int x = ((unsigned int)u) << 16;
    return __builtin_bit_cast(float, x);
}
__device__ __forceinline__ float sigm(float x) { return 1.f / (1.f + __expf(-x)); }
__device__ __forceinline__ float tanh_fast(float x) {
    x = fminf(fmaxf(x, -15.f), 15.f);
    float e = __expf(2.f * x);
    return (e - 1.f) / (e + 1.f);
}
__device__ __forceinline__ float dot4(float4 a, float4 b) {
    return a.x*b.x + a.y*b.y + a.z*b.z + a.w*b.w;
}

// recursive-halving wave reduction step (compile-time indices only)
#define REDSTEP(MASK, HALF)                                        \
    {                                                              \
        bool hi_ = (kc & MASK) != 0;                               \
        _Pragma("unroll")                                          \
        for (int i_ = 0; i_ < HALF; ++i_) {                        \
            float snd_ = hi_ ? a[i_] : a[i_ + HALF];               \
            float kp_  = hi_ ? a[i_ + HALF] : a[i_];               \
            a[i_] = kp_ + __shfl_xor(snd_, MASK);                  \
        }                                                          \
    }

// ---------- tiny prep kernels ----------
__global__ void prep_bias(const float* __restrict__ bihf, const float* __restrict__ bhhf,
                          const float* __restrict__ bihb, const float* __restrict__ bhhb,
                          const float* __restrict__ bihd, const float* __restrict__ bhhd,
                          float* __restrict__ bf_, float* __restrict__ bb_, float* __restrict__ bd_) {
    int id = blockIdx.x * 256 + threadIdx.x;     // 12288
    int mt = id >> 12, n = id & 4095;
    if (mt == 0) bf_[n] = bihf[n] + bhhf[n];
    else if (mt == 1) bb_[n] = bihb[n] + bhhb[n];
    else bd_[n] = bihd[n] + bhhd[n];
}

// embedding gather + bf16 split (x and y)
__global__ void embed_split(const int* __restrict__ inputs, const int* __restrict__ targets,
                            const float* __restrict__ es, const float* __restrict__ et,
                            ushortT* __restrict__ x1, ushortT* __restrict__ x2,
                            ushortT* __restrict__ y1, ushortT* __restrict__ y2) {
    int row = blockIdx.x;            // 0..4095
    int tid = threadIdx.x;           // 128
    bool isx = row < 2048;
    int r = isx ? row : row - 2048;
    int idx = isx ? inputs[r] : targets[r];
    const float* src = (isx ? es : et) + (size_t)idx * 512;
    float4 v = *(const float4*)&src[tid * 4];
    ushort4 hi, lo;
    hi.x = f2bf(v.x); lo.x = f2bf(v.x - bf2f(hi.x));
    hi.y = f2bf(v.y); lo.y = f2bf(v.y - bf2f(hi.y));
    hi.z = f2bf(v.z); lo.z = f2bf(v.z - bf2f(hi.z));
    hi.w = f2bf(v.w); lo.w = f2bf(v.w - bf2f(hi.w));
    ushortT* o1 = isx ? x1 : y1;
    ushortT* o2 = isx ? x2 : y2;
    *(ushort4*)&o1[(size_t)r * 512 + tid * 4] = hi;
    *(ushort4*)&o2[(size_t)r * 512 + tid * 4] = lo;
}

__global__ void split_pair(const float* __restrict__ in, ushortT* __restrict__ o1,
                           ushortT* __restrict__ o2, int n4) {
    for (int i = blockIdx.x * blockDim.x + threadIdx.x; i < n4; i += gridDim.x * blockDim.x) {
        float4 v = ((const float4*)in)[i];
        ushort4 hi, lo;
        hi.x = f2bf(v.x); lo.x = f2bf(v.x - bf2f(hi.x));
        hi.y = f2bf(v.y); lo.y = f2bf(v.y - bf2f(hi.y));
        hi.z = f2bf(v.z); lo.z = f2bf(v.z - bf2f(hi.z));
        hi.w = f2bf(v.w); lo.w = f2bf(v.w - bf2f(hi.w));
        ((ushort4*)o1)[i] = hi;
        ((ushort4*)o2)[i] = lo;
    }
}

__global__ void conv_single(const float* __restrict__ in, ushortT* __restrict__ o1, int n4) {
    for (int i = blockIdx.x * blockDim.x + threadIdx.x; i < n4; i += gridDim.x * blockDim.x) {
        float4 v = ((const float4*)in)[i];
        ushort4 hi;
        hi.x = f2bf(v.x); hi.y = f2bf(v.y); hi.z = f2bf(v.z); hi.w = f2bf(v.w);
        ((ushort4*)o1)[i] = hi;
    }
}

// Wc[:, :1024] split (row stride 3072)
__global__ void wc_split(const float* __restrict__ Wc, ushortT* __restrict__ o1, ushortT* __restrict__ o2) {
    int id = blockIdx.x * 256 + threadIdx.x;   // 1024*256
    int n = id >> 8, k4 = id & 255;
    float4 v = *(const float4*)&Wc[(size_t)n * 3072 + k4 * 4];
    ushort4 hi, lo;
    hi.x = f2bf(v.x); lo.x = f2bf(v.x - bf2f(hi.x));
    hi.y = f2bf(v.y); lo.y = f2bf(v.y - bf2f(hi.y));
    hi.z = f2bf(v.z); lo.z = f2bf(v.z - bf2f(hi.z));
    hi.w = f2bf(v.w); lo.w = f2bf(v.w - bf2f(hi.w));
    *(ushort4*)&o1[(size_t)n * 1024 + k4 * 4] = hi;
    *(ushort4*)&o2[(size_t)n * 1024 + k4 * 4] = lo;
}

// Whh (4096x1024) -> wt3[dir][k>>2][col][gate][k&3]  (fp32)
__global__ __launch_bounds__(256, 1) void transpose_whh(
    const float* __restrict__ Wf, const float* __restrict__ Wb, const float* __restrict__ Wd,
    float* __restrict__ wt3) {
    __shared__ float lds[64 * 132];
    int bx = blockIdx.x;             // 3*32*16 = 1536
    int d = bx >> 9;
    int rem = bx & 511;
    int kt = rem >> 4;               // 0..31 : 32-k tile
    int ct = rem & 15;               // 0..15 : 64-col tile
    const float* W = (d == 0) ? Wf : (d == 1) ? Wb : Wd;
    float* out = wt3 + (size_t)d * 4194304;
    int tid = threadIdx.x;
#pragma unroll
    for (int i = 0; i < 8; ++i) {
        int id = i * 256 + tid;
        int k8 = id & 7;             // float4 over k
        int rc = id >> 3;
        int g = rc >> 6, c = rc & 63;
        float4 v = *(const float4*)&W[(size_t)(g * 1024 + ct * 64 + c) * 1024 + kt * 32 + k8 * 4];
        lds[c * 132 + (k8 * 4 + 0) * 4 + g] = v.x;
        lds[c * 132 + (k8 * 4 + 1) * 4 + g] = v.y;
        lds[c * 132 + (k8 * 4 + 2) * 4 + g] = v.z;
        lds[c * 132 + (k8 * 4 + 3) * 4 + g] = v.w;
    }
    __syncthreads();
#pragma unroll
    for (int i = 0; i < 8; ++i) {
        int id = i * 256 + tid;
        int k4l = id >> 8;           // 0..7
        int rem2 = id & 255;
        int c = rem2 >> 2, g = rem2 & 3;
        float4 v;
        v.x = lds[c * 132 + (k4l * 4 + 0) * 4 + g];
        v.y = lds[c * 132 + (k4l * 4 + 1) * 4 + g];
        v.z = lds[c * 132 + (k4l * 4 + 2) * 4 + g];
        v.w = lds[c * 132 + (k4l * 4 + 3) * 4 + g];
        *(float4*)&out[(size_t)((kt * 8 + k4l) * 1024 + ct * 64 + c) * 16 + g * 4] = v;
    }
}

// ---------- MFMA GEMM: C[m][n] = sum_k A[m][k]*B[n][k] (+ bias / epilogue) ----------
// MODE 0: split3 (A1B1+A1B2+A2B1), C = acc + bias[n]
// MODE 1: split3, C = tanh(acc + bias[(m>>6)*1024 + n]); dual store f32 + bf16
// MODE 2: single (A1B1), C = acc + bias[n]
template <int MODE>
__global__ __launch_bounds__(256, 1) void gemm_bt(
    const ushortT* __restrict__ A1, const ushortT* __restrict__ A2,
    const ushortT* __restrict__ B1, const ushortT* __restrict__ B2,
    float* __restrict__ C, ushortT* __restrict__ Cb,
    const float* __restrict__ bias, int M, int N, int K) {
    constexpr int NBUF = (MODE == 2) ? 2 : 4;
    __shared__ __align__(16) ushortT smem[NBUF * 128 * 40];
    ushortT* sA1 = smem;
    ushortT* sB1 = smem + 128 * 40;
    ushortT* sA2 = smem + 2 * 128 * 40;   // unused when MODE==2
    ushortT* sB2 = smem + 3 * 128 * 40;

    const int tid = threadIdx.x;
    const int bm = blockIdx.y, bn = blockIdx.x;
    const int w = tid >> 6, lane = tid & 63;
    const int wm = (w & 1) * 64, wn = (w >> 1) * 64;
    const int lr = lane & 15, lq = lane >> 4;

    f32x4 acc[4][4] = {};
    const int nkt = K >> 5;
    for (int kt = 0; kt < nkt; ++kt) {
        __syncthreads();
#pragma unroll
        for (int i = 0; i < 2; ++i) {
            int id = tid + i * 256;
            int row = id >> 2, kc = id & 3;
            int so = row * 40 + kc * 8;
            size_t goA = (size_t)(bm * 128 + row) * K + kt * 32 + kc * 8;
            size_t goB = (size_t)(bn * 128 + row) * K + kt * 32 + kc * 8;
            *(uint4*)&sA1[so] = *(const uint4*)&A1[goA];
            *(uint4*)&sB1[so] = *(const uint4*)&B1[goB];
            if (MODE != 2) {
                *(uint4*)&sA2[so] = *(const uint4*)&A2[goA];
                *(uint4*)&sB2[so] = *(const uint4*)&B2[goB];
            }
        }
        __syncthreads();
        short8 a1[4], b1[4];
#pragma unroll
        for (int i = 0; i < 4; ++i) {
            a1[i] = *(const short8*)&sA1[(wm + i * 16 + lr) * 40 + lq * 8];
            b1[i] = *(const short8*)&sB1[(wn + i * 16 + lr) * 40 + lq * 8];
        }
        if (MODE == 2) {
#pragma unroll
            for (int mt = 0; mt < 4; ++mt)
#pragma unroll
                for (int nt = 0; nt < 4; ++nt)
                    acc[mt][nt] = __builtin_amdgcn_mfma_f32_16x16x32_bf16(a1[mt], b1[nt], acc[mt][nt], 0, 0, 0);
        } else {
            short8 a2[4], b2[4];
#pragma unroll
            for (int i = 0; i < 4; ++i) {
                a2[i] = *(const short8*)&sA2[(wm + i * 16 + lr) * 40 + lq * 8];
                b2[i] = *(const short8*)&sB2[(wn + i * 16 + lr) * 40 + lq * 8];
            }
#pragma unroll
            for (int mt = 0; mt < 4; ++mt)
#pragma unroll
                for (int nt = 0; nt < 4; ++nt) {
                    f32x4 a = acc[mt][nt];
                    a = __builtin_amdgcn_mfma_f32_16x16x32_bf16(a2[mt], b1[nt], a, 0, 0, 0);
                    a = __builtin_amdgcn_mfma_f32_16x16x32_bf16(a1[mt], b2[nt], a, 0, 0, 0);
                    a = __builtin_amdgcn_mfma_f32_16x16x32_bf16(a1[mt], b1[nt], a, 0, 0, 0);
                    acc[mt][nt] = a;
                }
        }
    }
    // epilogue; C row=m=(lane>>4)*4+reg, col=n=lane&15 (verified gfx950 mapping)
#pragma unroll
    for (int nt = 0; nt < 4; ++nt) {
        int gn = bn * 128 + wn + nt * 16 + lr;
        float bv = (MODE == 1) ? 0.f : bias[gn];
#pragma unroll
        for (int mt = 0; mt < 4; ++mt) {
            int gmb = bm * 128 + wm + mt * 16 + lq * 4;
#pragma unroll
            for (int r = 0; r < 4; ++r) {
                int gm = gmb + r;
                float v = acc[mt][nt][r];
                if (MODE == 1) {
                    v += bias[(gm >> 6) * 1024 + gn];
                    v = tanhf(v);
                    C[(size_t)gm * N + gn] = v;
                    Cb[(size_t)gm * N + gn] = f2bf(v);
                } else {
                    C[(size_t)gm * N + gn] = v + bv;
                }
            }
        }
    }
}

// ---------- encoder: fused fwd+bwd LSTM, register-resident weights ----------
// 256 wgs x 512 threads. Block = (dir, 8 cols). Thread = (col, b-half, kc):
// holds w[4 gates][32 k] in 128 VGPRs (loaded once), accumulates 16 b x 4 g.
// Per step: stage h (128 KB) to swizzled LDS, 2048 reg-FMA, shfl-halving reduce.
__global__ __launch_bounds__(512, 2) void encoder_kernel(
    const float* __restrict__ wt3,       // [2][256][1024][16]
    const float* __restrict__ Gf, const float* __restrict__ Gb,
    float* __restrict__ ench,            // [2 buf][2 dir][32768]
    float* __restrict__ cfin,            // [32768] (dir1 final c)
    float* __restrict__ applied,         // [32][2048]
    float* __restrict__ dech,            // [2][32768]
    float* __restrict__ cdec) {          // [32768]
    cg::grid_group grid = cg::this_grid();
    const int wg = blockIdx.x;           // 256
    const int dir = wg & 1;
    const int cb8 = wg >> 1;             // 0..127
    const int tid = threadIdx.x;         // 0..511
    const int wv = tid >> 6;             // 0..7
    const int lane = tid & 63;
    const int grp = wv * 2 + (lane >> 5);  // 16 groups = 8 cols x 2 b-halves
    const int colg = grp >> 1;           // 0..7
    const int bh = grp & 1;              // 0..1
    const int kc = lane & 31;            // k-chunk (32 k each)
    const int col = cb8 * 8 + colg;
    const bool own = ((kc & 1) == 0);
    const int b_own = bh * 16 + (kc >> 1);
    const float* W = wt3 + (size_t)dir * 4194304;
    const float* G = dir ? Gb : Gf;
    __shared__ __align__(16) float lh[32768];   // 128 KB swizzled h

    // load weight slice into registers: w4[gate][k4] = W[k4g][col][gate][0..3]
    float4 w4[4][8];
#pragma unroll
    for (int g = 0; g < 4; ++g)
#pragma unroll
        for (int k4 = 0; k4 < 8; ++k4)
            w4[g][k4] = *(const float4*)&W[(size_t)(kc * 8 + k4) * 16384 + col * 16 + g * 4];

    float cc = 0.f, hsum = 0.f, hn = 0.f;
    const int ht4 = (col >> 2) * 128 + b_own * 4 + (col & 3);
    for (int t = 0; t < 64; ++t) {
        const int tg = dir ? (63 - t) : t;
        float g0 = 0.f, g1 = 0.f, g2 = 0.f, g3 = 0.f;
        if (own) {
            const size_t mo = (size_t)(b_own * 64 + tg) * 4096 + col;
            g0 = G[mo]; g1 = G[mo + 1024]; g2 = G[mo + 2048]; g3 = G[mo + 3072];
        }
        float a[64];
#pragma unroll
        for (int j = 0; j < 64; ++j) a[j] = 0.f;
        if (t > 0) {
            // stage h into LDS (swizzled); global read coalesced
            const float4* src = (const float4*)(ench + (size_t)((((t + 1) & 1) * 2) + dir) * 32768);
#pragma unroll
            for (int i = 0; i < 16; ++i) {
                int f4 = tid + i * 512;
                int q = f4 >> 5, b = f4 & 31;
                int idx4 = b * 256 + q;
                int sw = idx4 ^ (((idx4 >> 3) ^ (idx4 >> 8) ^ (idx4 >> 11)) & 7);
                *(float4*)&lh[sw * 4] = src[f4];
            }
            __syncthreads();
#pragma unroll
            for (int b = 0; b < 16; ++b) {
                const int gb = bh * 16 + b;
                const int cswz = (kc ^ gb ^ (gb >> 3)) & 7;
                const float* bb = &lh[(gb * 256 + kc * 8) * 4];
#pragma unroll
                for (int k4 = 0; k4 < 8; ++k4) {
                    float4 hv = *(const float4*)&bb[(k4 ^ cswz) * 4];
#pragma unroll
                    for (int g = 0; g < 4; ++g) {
                        a[b * 4 + g] = fmaf(hv.x, w4[g][k4].x, a[b * 4 + g]);
                        a[b * 4 + g] = fmaf(hv.y, w4[g][k4].y, a[b * 4 + g]);
                        a[b * 4 + g] = fmaf(hv.z, w4[g][k4].z, a[b * 4 + g]);
                        a[b * 4 + g] = fmaf(hv.w, w4[g][k4].w, a[b * 4 + g]);
                    }
                }
            }
        }
        // reduce over 32 kc lanes: 64 accs -> lane kc holds j=2kc,2kc+1 (j=b*4+g)
        REDSTEP(16, 32) REDSTEP(8, 16) REDSTEP(4, 8) REDSTEP(2, 4) REDSTEP(1, 2)
        float gg_ = __shfl_xor(a[0], 1);
        float go_ = __shfl_xor(a[1], 1);
        if (own) {
            float gi = g0 + a[0];
            float gf = g1 + a[1];
            float gg = g2 + gg_;
            float go = g3 + go_;
            float i_ = sigm(gi), f_ = sigm(gf), g_ = tanh_fast(gg), o_ = sigm(go);
            cc = f_ * cc + i_ * g_;
            hn = o_ * tanh_fast(cc);
            hsum += hn;
            float* hw = ench + (size_t)(((t & 1) * 2) + dir) * 32768;
            hw[ht4] = hn;
            if (t == 63 && dir == 1) cfin[b_own * 1024 + col] = cc;
        }
        grid.sync();
    }
    if (own) {
        applied[b_own * 2048 + dir * 1024 + col] = hsum;
        if (dir == 0) {
            const float* h1d = ench + (size_t)(1 * 2 + 1) * 32768;   // buf1, dir1
            dech[32768 + ht4] = hn + h1d[ht4];                       // seed decoder buf1
            cdec[b_own * 1024 + col] = cc + cfin[b_own * 1024 + col];
        }
    }
}

// ---------- decoder LSTM: register-resident weights ----------
// 256 wgs x 512 threads. Block = 4 cols. Thread = (col, b-quarter, kc):
// w[4 gates][32 k] in 128 VGPRs; accumulates 8 b x 4 g; shfl-halving reduce.
__global__ __launch_bounds__(512, 2) void decoder_kernel(
    const float* __restrict__ wt3d,      // [256][1024][16]
    const float* __restrict__ G,
    float* __restrict__ dech,            // [2][32768]
    const float* __restrict__ cdec,
    float* __restrict__ hall,            // [2048][1024] f32
    ushortT* __restrict__ h1, ushortT* __restrict__ h2) {
    cg::grid_group grid = cg::this_grid();
    const int wg = blockIdx.x;           // 256
    const int tid = threadIdx.x;         // 0..511
    const int wv = tid >> 6;
    const int lane = tid & 63;
    const int grp = wv * 2 + (lane >> 5);  // 16 groups = 4 cols x 4 b-quarters
    const int colg = grp >> 2;           // 0..3
    const int bh = grp & 3;              // 0..3
    const int kc = lane & 31;
    const int col = wg * 4 + colg;       // 0..1023
    const bool own = ((kc & 3) == 0);
    const int b_own = bh * 8 + (kc >> 2);
    __shared__ __align__(16) float lh[32768];

    float4 w4[4][8];
#pragma unroll
    for (int g = 0; g < 4; ++g)
#pragma unroll
        for (int k4 = 0; k4 < 8; ++k4)
            w4[g][k4] = *(const float4*)&wt3d[(size_t)(kc * 8 + k4) * 16384 + col * 16 + g * 4];

    float cc = own ? cdec[b_own * 1024 + col] : 0.f;
    const int ht4 = (col >> 2) * 128 + b_own * 4 + (col & 3);
    for (int t = 0; t < 64; ++t) {
        float g0 = 0.f, g1 = 0.f, g2 = 0.f, g3 = 0.f;
        if (own) {
            const size_t mo = (size_t)(b_own * 64 + t) * 4096 + col;
            g0 = G[mo]; g1 = G[mo + 1024]; g2 = G[mo + 2048]; g3 = G[mo + 3072];
        }
        float a[32];
#pragma unroll
        for (int j = 0; j < 32; ++j) a[j] = 0.f;
        {
            const float4* src = (const float4*)(dech + (size_t)((t + 1) & 1) * 32768);
#pragma unroll
            for (int i = 0; i < 16; ++i) {
                int f4 = tid + i * 512;
                int q = f4 >> 5, b = f4 & 31;
                int idx4 = b * 256 + q;
                int sw = idx4 ^ (((idx4 >> 3) ^ (idx4 >> 8) ^ (idx4 >> 11)) & 7);
                *(float4*)&lh[sw * 4] = src[f4];
            }
            __syncthreads();
#pragma unroll
            for (int b = 0; b < 8; ++b) {
                const int gb = bh * 8 + b;
                const int cswz = (kc ^ gb ^ (gb >> 3)) & 7;
                const float* bb = &lh[(gb * 256 + kc * 8) * 4];
#pragma unroll
                for (int k4 = 0; k4 < 8; ++k4) {
                    float4 hv = *(const float4*)&bb[(k4 ^ cswz) * 4];
#pragma unroll
                    for (int g = 0; g < 4; ++g) {
                        a[b * 4 + g] = fmaf(hv.x, w4[g][k4].x, a[b * 4 + g]);
                        a[b * 4 + g] = fmaf(hv.y, w4[g][k4].y, a[b * 4 + g]);
                        a[b * 4 + g] = fmaf(hv.z, w4[g][k4].z, a[b * 4 + g]);
                        a[b * 4 + g] = fmaf(hv.w, w4[g][k4].w, a[b * 4 + g]);
                    }
                }
            }
        }
        // reduce over 32 kc lanes: 32 accs -> lane kc holds j=kc (j=b*4+g)
        REDSTEP(16, 16) REDSTEP(8, 8) REDSTEP(4, 4) REDSTEP(2, 2) REDSTEP(1, 1)
        float xf = __shfl_xor(a[0], 1);
        float xg = __shfl_xor(a[0], 2);
        float xo = __shfl_xor(a[0], 3);
        if (own) {
            float gi = g0 + a[0];
            float gf = g1 + xf;
            float gg = g2 + xg;
            float go = g3 + xo;
            float i_ = sigm(gi), f_ = sigm(gf), g_ = tanh_fast(gg), o_ = sigm(go);
            cc = f_ * cc + i_ * g_;
            float hn = o_ * tanh_fast(cc);
            dech[(size_t)(t & 1) * 32768 + ht4] = hn;
            size_t ho = (size_t)(b_own * 64 + t) * 1024 + col;
            hall[ho] = hn;
            ushortT hh = f2bf(hn);
            h1[ho] = hh;
            h2[ho] = f2bf(hn - bf2f(hh));
        }
        grid.sync();
    }
}

// ---------- ca[b][n] = bc[n] + sum_k applied[b][k] * Wc[n][1024+k] ----------
__global__ void ca_kernel(const float* __restrict__ applied, const float* __restrict__ Wc,
                          const float* __restrict__ bc, float* __restrict__ ca) {
    int id = blockIdx.x * 256 + threadIdx.x;   // 32768
    int b = id & 31, n = id >> 5;
    const float4* ap = (const float4*)(applied + b * 2048);
    const float4* wp = (const float4*)(Wc + (size_t)n * 3072 + 1024);
    float s = bc[n];
    for (int k = 0; k < 512; ++k) s += dot4(ap[k], wp[k]);
    ca[b * 1024 + n] = s;
}

// ---------- softmax + candidate collection (in-place on logits) ----------
__global__ __launch_bounds__(256, 1) void softmax_kernel(float* __restrict__ out,
                                                         int* __restrict__ cand, int* __restrict__ cnt) {
    int row = blockIdx.x, tid = threadIdx.x;
    float4* p4 = (float4*)(out + (size_t)row * 32000);
    float mx = -1e30f, sm = 0.f;
    for (int i = tid; i < 8000; i += 256) {
        float4 v = p4[i];
        float c;
        c = v.x; if (c > mx) { sm = sm * __expf(mx - c) + 1.f; mx = c; } else sm += __expf(c - mx);
        c = v.y; if (c > mx) { sm = sm * __expf(mx - c) + 1.f; mx = c; } else sm += __expf(c - mx);
        c = v.z; if (c > mx) { sm = sm * __expf(mx - c) + 1.f; mx = c; } else sm += __expf(c - mx);
        c = v.w; if (c > mx) { sm = sm * __expf(mx - c) + 1.f; mx = c; } else sm += __expf(c - mx);
    }
    __shared__ float rm[256], rs[256];
    rm[tid] = mx; rs[tid] = sm;
    __syncthreads();
    for (int off = 128; off > 0; off >>= 1) {
        if (tid < off) {
            float m1 = rm[tid], m2 = rm[tid + off], s1 = rs[tid], s2 = rs[tid + off];
            float mN = fmaxf(m1, m2);
            rm[tid] = mN;
            rs[tid] = s1 * __expf(m1 - mN) + s2 * __expf(m2 - mN);
        }
        __syncthreads();
    }
    float M = rm[0];
    float lse = M + __logf(rs[0]);
    __shared__ int lcnt;
    __shared__ int lcand[128];
    if (tid == 0) lcnt = 0;
    __syncthreads();
    const float thr = M - 6e-3f;
    for (int i = tid; i < 8000; i += 256) {
        float4 v = p4[i];
        float4 o;
        o.x = v.x - lse; o.y = v.y - lse; o.z = v.z - lse; o.w = v.w - lse;
        p4[i] = o;
        if (v.x >= thr) { int pos = atomicAdd(&lcnt, 1); if (pos < 128) lcand[pos] = i * 4 + 0; }
        if (v.y >= thr) { int pos = atomicAdd(&lcnt, 1); if (pos < 128) lcand[pos] = i * 4 + 1; }
        if (v.z >= thr) { int pos = atomicAdd(&lcnt, 1); if (pos < 128) lcand[pos] = i * 4 + 2; }
        if (v.w >= thr) { int pos = atomicAdd(&lcnt, 1); if (pos < 128) lcand[pos] = i * 4 + 3; }
    }
    __syncthreads();
    if (tid < 128 && tid < lcnt) cand[row * 128 + tid] = lcand[tid];
    if (tid == 0) cnt[row] = lcnt;
}

// ---------- fp32 argmax recheck: one wave per row ----------
__global__ __launch_bounds__(256, 1) void recheck_kernel(
    const float* __restrict__ outsf, const float* __restrict__ Wout, const float* __restrict__ bout,
    const int* __restrict__ cand, const int* __restrict__ cnt, float* __restrict__ preds) {
    int w = threadIdx.x >> 6, lane = threadIdx.x & 63;
    int row = blockIdx.x * 4 + w;
    const float4* ar = (const float4*)(outsf + (size_t)row * 1024);
    float4 a0 = ar[lane], a1 = ar[lane + 64], a2 = ar[lane + 128], a3 = ar[lane + 192];
    int n = cnt[row];
    float best = -1e30f;
    int bi = 0;
    if (n <= 128) {
        for (int ci = 0; ci < n; ++ci) {
            int j = cand[row * 128 + ci];
            const float4* wr = (const float4*)(Wout + (size_t)j * 1024);
            float s = dot4(a0, wr[lane]) + dot4(a1, wr[lane + 64]) + dot4(a2, wr[lane + 128]) + dot4(a3, wr[lane + 192]);
            for (int off = 32; off; off >>= 1) s += __shfl_xor(s, off);
            s += bout[j];
            if (s > best || (s == best && j < bi)) { best = s; bi = j; }
        }
    } else {
        for (int j = 0; j < 32000; ++j) {
            const float4* wr = (const float4*)(Wout + (size_t)j * 1024);
            float s = dot4(a0, wr[lane]) + dot4(a1, wr[lane + 64]) + dot4(a2, wr[lane + 128]) + dot4(a3, wr[lane + 192]);
            for (int off = 32; off; off >>= 1) s += __shfl_xor(s, off);
            s += bout[j];
            if (s > best || (s == best && j < bi)) { best = s; bi = j; }
        }
    }
    if (lane == 0) preds[row] = (float)bi;
}

// ---------- host ----------
static inline size_t al256(size_t x) { return (x + 255) & ~(size_t)255; }

extern "C" void kernel_launch(void* const* d_in, const int* in_sizes, int n_in,
                              void* d_out, int out_size, void* d_ws, size_t ws_size,
                              hipStream_t stream) {
    const int* inputs = (const int*)d_in[0];
    const int* targets = (const int*)d_in[1];
    const float* emb_src = (const float*)d_in[2];
    const float* Wih_f = (const float*)d_in[3];
    const float* Whh_f = (const float*)d_in[4];
    const float* bih_f = (const float*)d_in[5];
    const float* bhh_f = (const float*)d_in[6];
    const float* Wih_b = (const float*)d_in[7];
    const float* Whh_b = (const float*)d_in[8];
    const float* bih_b = (const float*)d_in[9];
    const float* bhh_b = (const float*)d_in[10];
    const float* emb_tgt = (const float*)d_in[11];
    const float* Wih_d = (const float*)d_in[12];
    const float* Whh_d = (const float*)d_in[13];
    const float* bih_d = (const float*)d_in[14];
    const float* bhh_d = (const float*)d_in[15];
    // d_in[16] = Wattn: provably unused (softmax over size-1 axis -> weights == 1)
    const float* Wc = (const float*)d_in[17];
    const float* bc = (const float*)d_in[18];
    const float* Wout = (const float*)d_in[19];
    const float* bout = (const float*)d_in[20];

    char* p = (char*)d_ws;
    size_t off = 0;
    auto carve = [&](size_t bytes) { void* r = p + off; off = al256(off + bytes); return r; };

    ushortT* x1 = (ushortT*)carve(2048ull * 512 * 2);
    ushortT* x2 = (ushortT*)carve(2048ull * 512 * 2);
    ushortT* y1 = (ushortT*)carve(2048ull * 512 * 2);
    ushortT* y2 = (ushortT*)carve(2048ull * 512 * 2);
    ushortT* wf1 = (ushortT*)carve(4096ull * 512 * 2);
    ushortT* wf2 = (ushortT*)carve(4096ull * 512 * 2);
    ushortT* wb1 = (ushortT*)carve(4096ull * 512 * 2);
    ushortT* wb2 = (ushortT*)carve(4096ull * 512 * 2);
    ushortT* wd1 = (ushortT*)carve(4096ull * 512 * 2);
    ushortT* wd2 = (ushortT*)carve(4096ull * 512 * 2);
    ushortT* wc1 = (ushortT*)carve(1024ull * 1024 * 2);
    ushortT* wc2 = (ushortT*)carve(1024ull * 1024 * 2);
    ushortT* woutb = (ushortT*)carve(32000ull * 1024 * 2);
    float* biasf = (float*)carve(4096ull * 4);
    float* biasb = (float*)carve(4096ull * 4);
    float* biasd = (float*)carve(4096ull * 4);
    float* wt3 = (float*)carve(3ull * 4194304 * 4);
    float* Gf = (float*)carve(2048ull * 4096 * 4);
    float* Gb = (float*)carve(2048ull * 4096 * 4);
    float* Gd = (float*)carve(2048ull * 4096 * 4);
    float* ench = (float*)carve(4ull * 32768 * 4);
    float* cfin = (float*)carve(32768ull * 4);
    float* applied = (float*)carve(65536ull * 4);
    float* dech = (float*)carve(2ull * 32768 * 4);
    float* cdec = (float*)carve(32768ull * 4);
    float* hall = (float*)carve(2048ull * 1024 * 4);
    ushortT* h1 = (ushortT*)carve(2048ull * 1024 * 2);
    ushortT* h2 = (ushortT*)carve(2048ull * 1024 * 2);
    float* ca = (float*)carve(32768ull * 4);
    float* outsf = (float*)carve(2048ull * 1024 * 4);
    ushortT* outsb = (ushortT*)carve(2048ull * 1024 * 2);
    int* cand = (int*)carve(2048ull * 128 * 4);
    int* cnt = (int*)carve(2048ull * 4);
    (void)ws_size;  // requires ~275 MB of workspace

    float* scores = (float*)d_out;
    float* preds = scores + 65536000ull;

    // prep
    prep_bias<<<48, 256, 0, stream>>>(bih_f, bhh_f, bih_b, bhh_b, bih_d, bhh_d, biasf, biasb, biasd);
    embed_split<<<4096, 128, 0, stream>>>(inputs, targets, emb_src, emb_tgt, x1, x2, y1, y2);
    split_pair<<<1024, 256, 0, stream>>>(Wih_f, wf1, wf2, 524288);
    split_pair<<<1024, 256, 0, stream>>>(Wih_b, wb1, wb2, 524288);
    split_pair<<<1024, 256, 0, stream>>>(Wih_d, wd1, wd2, 524288);
    wc_split<<<1024, 256, 0, stream>>>(Wc, wc1, wc2);
    conv_single<<<2048, 256, 0, stream>>>(Wout, woutb, 8192000);
    transpose_whh<<<1536, 256, 0, stream>>>(Whh_f, Whh_b, Whh_d, wt3);

    // gate precompute (split-bf16, fp32-grade)
    gemm_bt<0><<<dim3(32, 16), 256, 0, stream>>>(x1, x2, wf1, wf2, Gf, nullptr, biasf, 2048, 4096, 512);
    gemm_bt<0><<<dim3(32, 16), 256, 0, stream>>>(x1, x2, wb1, wb2, Gb, nullptr, biasb, 2048, 4096, 512);
    gemm_bt<0><<<dim3(32, 16), 256, 0, stream>>>(y1, y2, wd1, wd2, Gd, nullptr, biasd, 2048, 4096, 512);

    // encoder (cooperative, 512 threads/wg, register-resident weights)
    {
        void* args[] = {&wt3, &Gf, &Gb, &ench, &cfin, &applied, &dech, &cdec};
        hipLaunchCooperativeKernel((void*)encoder_kernel, dim3(256), dim3(512), args, 0, stream);
    }
    ca_kernel<<<128, 256, 0, stream>>>(applied, Wc, bc, ca);
    // decoder (cooperative, 512 threads/wg, register-resident weights)
    {
        const float* wt3d = wt3 + 2ull * 4194304;
        void* args[] = {&wt3d, &Gd, &dech, &cdec, &hall, &h1, &h2};
        hipLaunchCooperativeKernel((void*)decoder_kernel, dim3(256), dim3(512), args, 0, stream);
    }

    // outs = tanh(hall @ Wc_h^T + ca)  (split-bf16 + tanh, dual store)
    gemm_bt<1><<<dim3(8, 16), 256, 0, stream>>>(h1, h2, wc1, wc2, outsf, outsb, ca, 2048, 1024, 1024);
    // logits = outs @ Wout^T + bout  (single-pass bf16, straight into d_out)
    gemm_bt<2><<<dim3(250, 16), 256, 0, stream>>>(outsb, nullptr, woutb, nullptr, scores, nullptr, bout, 2048, 32000, 1024);
    // log_softmax in place + candidate collection
    softmax_kernel<<<2048, 256, 0, stream>>>(scores, cand, cnt);
    // fp32 argmax recheck -> preds
    recheck_kernel<<<512, 256, 0, stream>>>(outsf, Wout, bout, cand, cnt, preds);
}